// Round 10
// baseline (413.648 us; speedup 1.0000x reference)
//
#include <hip/hip_runtime.h>
#include <hip/hip_bf16.h>
#include <math.h>

#define N_NODES 50000
#define N_EDGES 800000
#define IN_F 256
#define OUT_F 64

#define BKT 256            // nodes per bucket
#define NB 196             // ceil(50000/256)
#define CAP 6144           // fixed per-bucket capacity (mean 4096, sigma 64)
#define PARTA_BLOCKS 400   // 800000/400 = 2000 edges/block

typedef __attribute__((ext_vector_type(8))) short bf16x8;
typedef __attribute__((ext_vector_type(4))) float f32x4;

__device__ __forceinline__ ushort f2bf(float x) {
    __hip_bfloat16 b = __float2bfloat16(x);   // RNE
    return *reinterpret_cast<ushort*>(&b);
}

// ---------------------------------------------------------------------------
// 0) prep: block 0 zeros bcntD+bcntS (392 ints); blocks 1..8 pack W into
//    bf16 MFMA B-frag layout (identical values to in-loop convert).
// ---------------------------------------------------------------------------
__global__ __launch_bounds__(256) void prep_kernel(int* __restrict__ bcnt,
                                                   const float* __restrict__ W,
                                                   ushort* __restrict__ Wpk) {
    const int tid = threadIdx.x;
    if (blockIdx.x == 0) {
        for (int i = tid; i < 2 * NB; i += 256) bcnt[i] = 0;
    } else {
        const int gid = (blockIdx.x - 1) * 256 + tid;   // 0..2047
        const int lane = gid & 63;
        const int ct = (gid >> 6) & 3;
        const int step = gid >> 8;
        const int kg = lane >> 4;
        const int n = lane & 15;
        const float* base = W + (size_t)(step * 32 + kg * 8) * OUT_F + ct * 16 + n;
        union { ushort u[8]; uint4 v; } pk;
        #pragma unroll
        for (int j = 0; j < 8; ++j) pk.u[j] = f2bf(base[(size_t)j * OUT_F]);
        ((uint4*)Wpk)[gid] = pk.v;
    }
}

// ---------------------------------------------------------------------------
// 1) partA: dual bucket-partition in one pass over the edge list.
//    dst-buckets: pairsD[b*CAP + i] = (dst&255)<<16 | src
//    src-buckets: srcloc[b*CAP + i] = src&255   (for degree counting)
//    Fixed CAP regions -> no scan/alloc needed anywhere.
// ---------------------------------------------------------------------------
__global__ __launch_bounds__(256) void partA_kernel(const int* __restrict__ src,
                                                    const int* __restrict__ dst,
                                                    int* __restrict__ bcntD,
                                                    int* __restrict__ bcntS,
                                                    uint* __restrict__ pairsD,
                                                    ushort* __restrict__ srcloc) {
    __shared__ int lcntD[NB], lbaseD[NB], lcntS[NB], lbaseS[NB];
    const int tid = threadIdx.x;
    const int EPB = N_EDGES / PARTA_BLOCKS;   // 2000
    const int n4 = EPB / 4;                   // 500

    for (int i = tid; i < NB; i += 256) { lcntD[i] = 0; lcntS[i] = 0; }
    __syncthreads();

    const int4* t4 = (const int4*)(dst + (size_t)blockIdx.x * EPB);
    const int4* s4 = (const int4*)(src + (size_t)blockIdx.x * EPB);

    for (int i = tid; i < n4; i += 256) {
        const int4 d = t4[i];
        const int4 s = s4[i];
        atomicAdd(&lcntD[d.x >> 8], 1); atomicAdd(&lcntS[s.x >> 8], 1);
        atomicAdd(&lcntD[d.y >> 8], 1); atomicAdd(&lcntS[s.y >> 8], 1);
        atomicAdd(&lcntD[d.z >> 8], 1); atomicAdd(&lcntS[s.z >> 8], 1);
        atomicAdd(&lcntD[d.w >> 8], 1); atomicAdd(&lcntS[s.w >> 8], 1);
    }
    __syncthreads();

    for (int i = tid; i < NB; i += 256) {
        int c = lcntD[i];
        lbaseD[i] = c ? atomicAdd(&bcntD[i], c) : 0;
        lcntD[i] = 0;
        c = lcntS[i];
        lbaseS[i] = c ? atomicAdd(&bcntS[i], c) : 0;
        lcntS[i] = 0;
    }
    __syncthreads();

    for (int i = tid; i < n4; i += 256) {
        const int4 d = t4[i];
        const int4 s = s4[i];
        int bx, off;
        #define PLACE(dd, ss)                                                      \
            bx = (dd) >> 8; off = atomicAdd(&lcntD[bx], 1);                        \
            pairsD[(size_t)bx * CAP + lbaseD[bx] + off] =                          \
                ((uint)((dd) & 255) << 16) | (uint)(ss);                           \
            bx = (ss) >> 8; off = atomicAdd(&lcntS[bx], 1);                        \
            srcloc[(size_t)bx * CAP + lbaseS[bx] + off] = (ushort)((ss) & 255);
        PLACE(d.x, s.x)
        PLACE(d.y, s.y)
        PLACE(d.z, s.z)
        PLACE(d.w, s.w)
        #undef PLACE
    }
}

// ---------------------------------------------------------------------------
// 2) degB: per src-bucket, LDS-count local occurrences -> outdeg (non-atomic
//    single-owner write; no zeroing, no flush atomics).
// ---------------------------------------------------------------------------
__global__ __launch_bounds__(256) void degB_kernel(const ushort* __restrict__ srcloc,
                                                   const int* __restrict__ bcntS,
                                                   int* __restrict__ outdeg) {
    __shared__ int cnt[BKT];
    const int tid = threadIdx.x;
    const int bb = blockIdx.x;
    cnt[tid] = 0;
    __syncthreads();
    const int n = bcntS[bb];
    const ushort* sp = srcloc + (size_t)bb * CAP;
    for (int i = tid; i < n; i += 256) atomicAdd(&cnt[sp[i]], 1);
    __syncthreads();
    const int node = bb * BKT + tid;
    if (node < N_NODES) outdeg[node] = cnt[tid];
}

// ---------------------------------------------------------------------------
// 3) h = bf16( norm_src * (feat @ W) ) via MFMA 16x16x32 bf16 (round-9).
//    Wave = 16 rows x 64 cols; block = 64 rows; grid = 782 (3 blocks/CU).
// ---------------------------------------------------------------------------
__global__ __launch_bounds__(256) void gemm_kernel(const float* __restrict__ feat,
                                                   const ushort* __restrict__ Wpk,
                                                   const int* __restrict__ outdeg,
                                                   ushort* __restrict__ h) {
    const int lane = threadIdx.x & 63;
    const int wave = threadIdx.x >> 6;
    const int m = lane & 15;
    const int g = lane >> 4;
    const int rowBase = blockIdx.x * 64 + wave * 16;

    f32x4 acc[4];
    #pragma unroll
    for (int ct = 0; ct < 4; ++ct) acc[ct] = (f32x4){0.f, 0.f, 0.f, 0.f};

    int arow = rowBase + m;
    if (arow >= N_NODES) arow = N_NODES - 1;   // clamp; stores guarded below
    const float* ap = feat + (size_t)arow * IN_F;
    const bf16x8* wp = (const bf16x8*)Wpk;

    #pragma unroll
    for (int step = 0; step < 8; ++step) {
        const int k0 = step * 32 + g * 8;
        const float4 a0 = *(const float4*)(ap + k0);
        const float4 a1 = *(const float4*)(ap + k0 + 4);
        bf16x8 aa;
        aa[0] = (short)f2bf(a0.x); aa[1] = (short)f2bf(a0.y);
        aa[2] = (short)f2bf(a0.z); aa[3] = (short)f2bf(a0.w);
        aa[4] = (short)f2bf(a1.x); aa[5] = (short)f2bf(a1.y);
        aa[6] = (short)f2bf(a1.z); aa[7] = (short)f2bf(a1.w);
        #pragma unroll
        for (int ct = 0; ct < 4; ++ct)
            acc[ct] = __builtin_amdgcn_mfma_f32_16x16x32_bf16(
                aa, wp[(step * 4 + ct) * 64 + lane], acc[ct], 0, 0, 0);
    }

    // C-frag: col = ct*16 + m, row = rowBase + g*4 + j   [m89 verified]
    #pragma unroll
    for (int j = 0; j < 4; ++j) {
        const int row = rowBase + g * 4 + j;
        if (row < N_NODES) {
            const float norm = rsqrtf(fmaxf((float)outdeg[row], 1.0f));
            #pragma unroll
            for (int ct = 0; ct < 4; ++ct)
                h[(size_t)row * OUT_F + ct * 16 + m] = f2bf(acc[ct][j] * norm);
        }
    }
}

// ---------------------------------------------------------------------------
// 4) gatherB: fused partB+gather+epilogue. One block per dst-bucket.
//    Wave per edge (lane = col): read h[src] row, ds_add_f32 into LDS
//    acc[256][64] (lane-stride -> 2-way bank alias = free). Epilogue:
//    norm+bias+sigmoid, coalesced 64 KB store.
// ---------------------------------------------------------------------------
__global__ __launch_bounds__(1024) void gatherB_kernel(const uint* __restrict__ pairsD,
                                                       const int* __restrict__ bcntD,
                                                       const ushort* __restrict__ h,
                                                       const float* __restrict__ b,
                                                       float* __restrict__ out) {
    __shared__ float accf[BKT * OUT_F];   // 64 KB
    __shared__ int cnt[BKT];
    const int tid = threadIdx.x;
    const int lane = tid & 63;
    const int wave = tid >> 6;            // 0..15
    const int bb = blockIdx.x;

    #pragma unroll
    for (int i = tid; i < BKT * OUT_F; i += 1024) accf[i] = 0.f;
    if (tid < BKT) cnt[tid] = 0;
    __syncthreads();

    const int n = bcntD[bb];
    const uint* pb = pairsD + (size_t)bb * CAP;
    #pragma unroll 4
    for (int i = wave; i < n; i += 16) {
        const uint p = pb[i];
        const int local = (int)(p >> 16);
        const int s = (int)(p & 0xFFFFu);
        const float f = __uint_as_float((uint)h[(size_t)s * OUT_F + lane] << 16);
        atomicAdd(&accf[local * OUT_F + lane], f);
        if (lane == 0) atomicAdd(&cnt[local], 1);
    }
    __syncthreads();

    const int c = tid & 63;
    #pragma unroll
    for (int r = tid >> 6; r < BKT; r += 16) {
        const int node = bb * BKT + r;
        if (node < N_NODES) {
            const float norm = rsqrtf(fmaxf((float)cnt[r], 1.0f));
            const float x = accf[r * OUT_F + c] * norm + b[c];
            out[(size_t)node * OUT_F + c] = 1.0f / (1.0f + expf(-x));
        }
    }
}

// ---------------------------------------------------------------------------
extern "C" void kernel_launch(void* const* d_in, const int* in_sizes, int n_in,
                              void* d_out, int out_size, void* d_ws, size_t ws_size,
                              hipStream_t stream) {
    const float* feat = (const float*)d_in[0];
    const int* src    = (const int*)d_in[1];
    const int* dst    = (const int*)d_in[2];
    const float* W    = (const float*)d_in[3];
    const float* b    = (const float*)d_in[4];
    float* out = (float*)d_out;

    char* ws = (char*)d_ws;
    size_t off = 0;
    ushort* h = (ushort*)(ws + off);        off += (size_t)N_NODES * OUT_F * 2;  // 6.4 MB
    int* outdeg = (int*)(ws + off);         off += (size_t)N_NODES * 4;          // 200 KB
    int* bcnt = (int*)(ws + off);           off += (size_t)2 * NB * 4;           // bcntD|bcntS
    ushort* Wpk = (ushort*)(ws + off);      off += (size_t)IN_F * OUT_F * 2;     // 32 KB
    uint* pairsD = (uint*)(ws + off);       off += (size_t)NB * CAP * 4;         // 4.8 MB
    ushort* srcloc = (ushort*)(ws + off);   off += (size_t)NB * CAP * 2;         // 2.4 MB
    int* bcntD = bcnt;
    int* bcntS = bcnt + NB;

    prep_kernel<<<9, 256, 0, stream>>>(bcnt, W, Wpk);

    partA_kernel<<<PARTA_BLOCKS, 256, 0, stream>>>(src, dst, bcntD, bcntS, pairsD, srcloc);

    degB_kernel<<<NB, 256, 0, stream>>>(srcloc, bcntS, outdeg);

    gemm_kernel<<<(N_NODES + 63) / 64, 256, 0, stream>>>(feat, Wpk, outdeg, h);

    gatherB_kernel<<<NB, 1024, 0, stream>>>(pairsD, bcntD, h, b, out);
}

// Round 11
// 90.258 us; speedup vs baseline: 4.5829x; 4.5829x over previous
//
#include <hip/hip_runtime.h>
#include <hip/hip_bf16.h>
#include <math.h>

#define N_NODES 50000
#define N_EDGES 800000
#define IN_F 256
#define OUT_F 64

#define BKT 256            // nodes per bucket
#define NB 196             // ceil(50000/256)
#define CAP 6144           // fixed per-bucket capacity (mean 4096, sigma 64)
#define PARTA_BLOCKS 400   // 800000/400 = 2000 edges/block

typedef __attribute__((ext_vector_type(8))) short bf16x8;
typedef __attribute__((ext_vector_type(4))) float f32x4;

__device__ __forceinline__ ushort f2bf(float x) {
    __hip_bfloat16 b = __float2bfloat16(x);   // RNE
    return *reinterpret_cast<ushort*>(&b);
}
__device__ __forceinline__ float bf_lo(uint v) { return __uint_as_float(v << 16); }
__device__ __forceinline__ float bf_hi(uint v) { return __uint_as_float(v & 0xffff0000u); }

// ---------------------------------------------------------------------------
// 0) prep: block 0 zeros bcntD+bcntS (392 ints); blocks 1..8 pack W into
//    bf16 MFMA B-frag layout (identical values to in-loop convert).
// ---------------------------------------------------------------------------
__global__ __launch_bounds__(256) void prep_kernel(int* __restrict__ bcnt,
                                                   const float* __restrict__ W,
                                                   ushort* __restrict__ Wpk) {
    const int tid = threadIdx.x;
    if (blockIdx.x == 0) {
        for (int i = tid; i < 2 * NB; i += 256) bcnt[i] = 0;
    } else {
        const int gid = (blockIdx.x - 1) * 256 + tid;   // 0..2047
        const int lane = gid & 63;
        const int ct = (gid >> 6) & 3;
        const int step = gid >> 8;
        const int kg = lane >> 4;
        const int n = lane & 15;
        const float* base = W + (size_t)(step * 32 + kg * 8) * OUT_F + ct * 16 + n;
        union { ushort u[8]; uint4 v; } pk;
        #pragma unroll
        for (int j = 0; j < 8; ++j) pk.u[j] = f2bf(base[(size_t)j * OUT_F]);
        ((uint4*)Wpk)[gid] = pk.v;
    }
}

// ---------------------------------------------------------------------------
// 1) partA: dual bucket-partition in one pass over the edge list.
//    dst-buckets: pairsD[b*CAP + i] = (dst&255)<<16 | src
//    src-buckets: srcloc[b*CAP + i] = src&255   (for degree counting)
// ---------------------------------------------------------------------------
__global__ __launch_bounds__(256) void partA_kernel(const int* __restrict__ src,
                                                    const int* __restrict__ dst,
                                                    int* __restrict__ bcntD,
                                                    int* __restrict__ bcntS,
                                                    uint* __restrict__ pairsD,
                                                    ushort* __restrict__ srcloc) {
    __shared__ int lcntD[NB], lbaseD[NB], lcntS[NB], lbaseS[NB];
    const int tid = threadIdx.x;
    const int EPB = N_EDGES / PARTA_BLOCKS;   // 2000
    const int n4 = EPB / 4;                   // 500

    for (int i = tid; i < NB; i += 256) { lcntD[i] = 0; lcntS[i] = 0; }
    __syncthreads();

    const int4* t4 = (const int4*)(dst + (size_t)blockIdx.x * EPB);
    const int4* s4 = (const int4*)(src + (size_t)blockIdx.x * EPB);

    for (int i = tid; i < n4; i += 256) {
        const int4 d = t4[i];
        const int4 s = s4[i];
        atomicAdd(&lcntD[d.x >> 8], 1); atomicAdd(&lcntS[s.x >> 8], 1);
        atomicAdd(&lcntD[d.y >> 8], 1); atomicAdd(&lcntS[s.y >> 8], 1);
        atomicAdd(&lcntD[d.z >> 8], 1); atomicAdd(&lcntS[s.z >> 8], 1);
        atomicAdd(&lcntD[d.w >> 8], 1); atomicAdd(&lcntS[s.w >> 8], 1);
    }
    __syncthreads();

    for (int i = tid; i < NB; i += 256) {
        int c = lcntD[i];
        lbaseD[i] = c ? atomicAdd(&bcntD[i], c) : 0;
        lcntD[i] = 0;
        c = lcntS[i];
        lbaseS[i] = c ? atomicAdd(&bcntS[i], c) : 0;
        lcntS[i] = 0;
    }
    __syncthreads();

    for (int i = tid; i < n4; i += 256) {
        const int4 d = t4[i];
        const int4 s = s4[i];
        int bx, off;
        #define PLACE(dd, ss)                                                      \
            bx = (dd) >> 8; off = atomicAdd(&lcntD[bx], 1);                        \
            pairsD[(size_t)bx * CAP + lbaseD[bx] + off] =                          \
                ((uint)((dd) & 255) << 16) | (uint)(ss);                           \
            bx = (ss) >> 8; off = atomicAdd(&lcntS[bx], 1);                        \
            srcloc[(size_t)bx * CAP + lbaseS[bx] + off] = (ushort)((ss) & 255);
        PLACE(d.x, s.x)
        PLACE(d.y, s.y)
        PLACE(d.z, s.z)
        PLACE(d.w, s.w)
        #undef PLACE
    }
}

// ---------------------------------------------------------------------------
// 2) degB: per src-bucket, LDS-count local occurrences -> outdeg (non-atomic
//    single-owner write; no zeroing, no flush atomics).
// ---------------------------------------------------------------------------
__global__ __launch_bounds__(256) void degB_kernel(const ushort* __restrict__ srcloc,
                                                   const int* __restrict__ bcntS,
                                                   int* __restrict__ outdeg) {
    __shared__ int cnt[BKT];
    const int tid = threadIdx.x;
    const int bb = blockIdx.x;
    cnt[tid] = 0;
    __syncthreads();
    const int n = bcntS[bb];
    const ushort* sp = srcloc + (size_t)bb * CAP;
    for (int i = tid; i < n; i += 256) atomicAdd(&cnt[sp[i]], 1);
    __syncthreads();
    const int node = bb * BKT + tid;
    if (node < N_NODES) outdeg[node] = cnt[tid];
}

// ---------------------------------------------------------------------------
// 3) partB: per dst-bucket — count locals, in-block exclusive scan,
//    write ptr/indeg (single-owner, non-atomic), place sorted_src within
//    the bucket's CAP region (scatter confined to ~12 KB).
// ---------------------------------------------------------------------------
__global__ __launch_bounds__(256) void partB_kernel(const uint* __restrict__ pairsD,
                                                    const int* __restrict__ bcntD,
                                                    int* __restrict__ ptr,
                                                    int* __restrict__ indeg,
                                                    ushort* __restrict__ sorted_src) {
    __shared__ int lcnt[BKT];
    __shared__ int loff[BKT];
    __shared__ int lcur[BKT];
    __shared__ int wtot[4];
    const int bb = blockIdx.x;
    const int tid = threadIdx.x;
    const int lane = tid & 63;
    const int wave = tid >> 6;

    lcnt[tid] = 0;
    __syncthreads();

    const int n = bcntD[bb];
    const uint* pb = pairsD + (size_t)bb * CAP;
    for (int i = tid; i < n; i += 256) atomicAdd(&lcnt[pb[i] >> 16], 1);
    __syncthreads();

    // block exclusive scan of lcnt[256]
    const int v = lcnt[tid];
    int incl = v;
    #pragma unroll
    for (int d = 1; d < 64; d <<= 1) {
        int u = __shfl_up(incl, d, 64);
        if (lane >= d) incl += u;
    }
    if (lane == 63) wtot[wave] = incl;
    __syncthreads();
    int woff = 0;
    #pragma unroll
    for (int w = 0; w < 4; ++w)
        if (w < wave) woff += wtot[w];
    const int ex = woff + incl - v;
    loff[tid] = ex;
    lcur[tid] = 0;
    const int node = bb * BKT + tid;
    if (node < N_NODES) { ptr[node] = bb * CAP + ex; indeg[node] = v; }
    __syncthreads();

    for (int i = tid; i < n; i += 256) {
        const uint p = pb[i];
        const int local = (int)(p >> 16);
        const int pos = atomicAdd(&lcur[local], 1);
        sorted_src[(size_t)bb * CAP + loff[local] + pos] = (ushort)(p & 0xFFFFu);
    }
}

// ---------------------------------------------------------------------------
// 4) h = bf16( norm_src * (feat @ W) ) via MFMA 16x16x32 bf16.
//    Wave = 16 rows x 64 cols; block = 64 rows; grid = 782 (3 blocks/CU).
// ---------------------------------------------------------------------------
__global__ __launch_bounds__(256) void gemm_kernel(const float* __restrict__ feat,
                                                   const ushort* __restrict__ Wpk,
                                                   const int* __restrict__ outdeg,
                                                   ushort* __restrict__ h) {
    const int lane = threadIdx.x & 63;
    const int wave = threadIdx.x >> 6;
    const int m = lane & 15;
    const int g = lane >> 4;
    const int rowBase = blockIdx.x * 64 + wave * 16;

    f32x4 acc[4];
    #pragma unroll
    for (int ct = 0; ct < 4; ++ct) acc[ct] = (f32x4){0.f, 0.f, 0.f, 0.f};

    int arow = rowBase + m;
    if (arow >= N_NODES) arow = N_NODES - 1;   // clamp; stores guarded below
    const float* ap = feat + (size_t)arow * IN_F;
    const bf16x8* wp = (const bf16x8*)Wpk;

    #pragma unroll
    for (int step = 0; step < 8; ++step) {
        const int k0 = step * 32 + g * 8;
        const float4 a0 = *(const float4*)(ap + k0);
        const float4 a1 = *(const float4*)(ap + k0 + 4);
        bf16x8 aa;
        aa[0] = (short)f2bf(a0.x); aa[1] = (short)f2bf(a0.y);
        aa[2] = (short)f2bf(a0.z); aa[3] = (short)f2bf(a0.w);
        aa[4] = (short)f2bf(a1.x); aa[5] = (short)f2bf(a1.y);
        aa[6] = (short)f2bf(a1.z); aa[7] = (short)f2bf(a1.w);
        #pragma unroll
        for (int ct = 0; ct < 4; ++ct)
            acc[ct] = __builtin_amdgcn_mfma_f32_16x16x32_bf16(
                aa, wp[(step * 4 + ct) * 64 + lane], acc[ct], 0, 0, 0);
    }

    // C-frag: col = ct*16 + m, row = rowBase + g*4 + j   [m89 verified]
    #pragma unroll
    for (int j = 0; j < 4; ++j) {
        const int row = rowBase + g * 4 + j;
        if (row < N_NODES) {
            const float norm = rsqrtf(fmaxf((float)outdeg[row], 1.0f));
            #pragma unroll
            for (int ct = 0; ct < 4; ++ct)
                h[(size_t)row * OUT_F + ct * 16 + m] = f2bf(acc[ct][j] * norm);
        }
    }
}

// ---------------------------------------------------------------------------
// 5) Gather + epilogue: one wave per dst node, QUARTER-wave per edge
//    (16 lanes x 8 B = full 128 B h-row), 4 edges per iteration.
// ---------------------------------------------------------------------------
__global__ __launch_bounds__(256) void gather_kernel(const int* __restrict__ ptr,
                                                     const int* __restrict__ indeg,
                                                     const ushort* __restrict__ sorted_src,
                                                     const ushort* __restrict__ h,
                                                     const float* __restrict__ b,
                                                     float* __restrict__ out) {
    const int lane = threadIdx.x & 63;
    const int q = lane & 15;           // col group: cols q*4 .. q*4+3
    const int g = lane >> 4;           // edge slot 0..3
    int nid = (int)((blockIdx.x * (size_t)blockDim.x + threadIdx.x) >> 6);
    if (nid >= N_NODES) return;
    nid = __builtin_amdgcn_readfirstlane(nid);

    const int beg = ptr[nid];
    const int deg = indeg[nid];

    float a0 = 0.f, a1 = 0.f, a2 = 0.f, a3 = 0.f;
    const int nfull = deg >> 2;
    int e = beg + g;
    #pragma unroll 4
    for (int i = 0; i < nfull; ++i) {
        const int s = (int)sorted_src[e];
        e += 4;
        const uint2 v = *(const uint2*)(h + (size_t)s * OUT_F + q * 4);
        a0 += bf_lo(v.x); a1 += bf_hi(v.x);
        a2 += bf_lo(v.y); a3 += bf_hi(v.y);
    }
    const int rem = deg & 3;
    if (g < rem) {
        const int s = (int)sorted_src[beg + (deg & ~3) + g];
        const uint2 v = *(const uint2*)(h + (size_t)s * OUT_F + q * 4);
        a0 += bf_lo(v.x); a1 += bf_hi(v.x);
        a2 += bf_lo(v.y); a3 += bf_hi(v.y);
    }
    // combine the 4 edge-slot groups (flip g bits: xor 16, xor 32)
    a0 += __shfl_xor(a0, 16, 64); a1 += __shfl_xor(a1, 16, 64);
    a2 += __shfl_xor(a2, 16, 64); a3 += __shfl_xor(a3, 16, 64);
    a0 += __shfl_xor(a0, 32, 64); a1 += __shfl_xor(a1, 32, 64);
    a2 += __shfl_xor(a2, 32, 64); a3 += __shfl_xor(a3, 32, 64);

    if (g == 0) {
        const float norm = rsqrtf(fmaxf((float)deg, 1.0f));
        const float4 bb = *(const float4*)(b + q * 4);
        float4 o;
        o.x = 1.0f / (1.0f + expf(-(a0 * norm + bb.x)));
        o.y = 1.0f / (1.0f + expf(-(a1 * norm + bb.y)));
        o.z = 1.0f / (1.0f + expf(-(a2 * norm + bb.z)));
        o.w = 1.0f / (1.0f + expf(-(a3 * norm + bb.w)));
        *(float4*)(out + (size_t)nid * OUT_F + q * 4) = o;
    }
}

// ---------------------------------------------------------------------------
extern "C" void kernel_launch(void* const* d_in, const int* in_sizes, int n_in,
                              void* d_out, int out_size, void* d_ws, size_t ws_size,
                              hipStream_t stream) {
    const float* feat = (const float*)d_in[0];
    const int* src    = (const int*)d_in[1];
    const int* dst    = (const int*)d_in[2];
    const float* W    = (const float*)d_in[3];
    const float* b    = (const float*)d_in[4];
    float* out = (float*)d_out;

    char* ws = (char*)d_ws;
    size_t off = 0;
    ushort* h = (ushort*)(ws + off);        off += (size_t)N_NODES * OUT_F * 2;  // 6.4 MB
    int* outdeg = (int*)(ws + off);         off += (size_t)N_NODES * 4;          // 200 KB
    int* indeg = (int*)(ws + off);          off += (size_t)N_NODES * 4;          // 200 KB
    int* ptr = (int*)(ws + off);            off += (size_t)N_NODES * 4;          // 200 KB
    int* bcnt = (int*)(ws + off);           off += (size_t)2 * NB * 4;           // bcntD|bcntS
    ushort* Wpk = (ushort*)(ws + off);      off += (size_t)IN_F * OUT_F * 2;     // 32 KB
    uint* pairsD = (uint*)(ws + off);       off += (size_t)NB * CAP * 4;         // 4.8 MB
    ushort* srcloc = (ushort*)(ws + off);   off += (size_t)NB * CAP * 2;         // 2.4 MB
    ushort* sorted_src = (ushort*)(ws + off); off += (size_t)NB * CAP * 2;       // 2.4 MB
    int* bcntD = bcnt;
    int* bcntS = bcnt + NB;

    prep_kernel<<<9, 256, 0, stream>>>(bcnt, W, Wpk);

    partA_kernel<<<PARTA_BLOCKS, 256, 0, stream>>>(src, dst, bcntD, bcntS, pairsD, srcloc);

    degB_kernel<<<NB, 256, 0, stream>>>(srcloc, bcntS, outdeg);

    partB_kernel<<<NB, 256, 0, stream>>>(pairsD, bcntD, ptr, indeg, sorted_src);

    gemm_kernel<<<(N_NODES + 63) / 64, 256, 0, stream>>>(feat, Wpk, outdeg, h);

    gather_kernel<<<(N_NODES * 64 + 255) / 256, 256, 0, stream>>>(ptr, indeg, sorted_src, h, b, out);
}